// Round 1
// baseline (1031.792 us; speedup 1.0000x reference)
//
#include <hip/hip_runtime.h>
#include <hip/hip_bf16.h>

#define JN 17
#define NTV 9
#define SB 8      // samples per tile
#define BLK 256

__device__ __forceinline__ unsigned bf16b(float x){
    unsigned b = __float_as_uint(x);
    return (b + 0x7FFFu + ((b >> 16) & 1u)) >> 16;
}
__device__ __forceinline__ float lo16(unsigned u){ return __uint_as_float(u << 16); }
__device__ __forceinline__ float hi16(unsigned u){ return __uint_as_float(u & 0xFFFF0000u); }
__device__ __forceinline__ float lrelu(float x){ return x > 0.f ? x : 0.01f * x; }

__global__ __launch_bounds__(BLK, 2)
void score_kernel(const float* __restrict__ x, const void* __restrict__ mraw,
                  const float* __restrict__ pos,
                  const float* __restrict__ Wup, const float* __restrict__ bup,
                  const float* __restrict__ Wud, const float* __restrict__ bud,
                  const float* __restrict__ Wq,  const float* __restrict__ bq,
                  const float* __restrict__ Wk,  const float* __restrict__ bk,
                  const float* __restrict__ Wv,  const float* __restrict__ bv,
                  const float* __restrict__ Wd1, const float* __restrict__ bd1,
                  const float* __restrict__ Wd2, const float* __restrict__ bd2,
                  const float* __restrict__ Ws,  const float* __restrict__ bs,
                  float* __restrict__ out, int B)
{
    __shared__ unsigned s_wup[544*18];            // W_up^T, bf16 pairs, row=col(544), 17 pairs + pad
    __shared__ unsigned s_wud[32*33];             // W_ud^T, row=h(32), 32 pairs + pad
    __shared__ unsigned s_wq[32*17], s_wk[32*17], s_wv[32*17], s_wd1[32*17], s_wd2[32*17];
    __shared__ float s_pp[17*33];                 // positions @ W_ud[32:64]  (precomputed)
    __shared__ float s_bup[544];
    __shared__ float s_bud[32], s_bq[32], s_bk[32], s_bv[32], s_bd1[32], s_bd2[32], s_ws[32];
    __shared__ float s_xs[SB*36];
    __shared__ int   s_perm[SB*20];
    __shared__ int   s_mode;

    const int tid = threadIdx.x;

    // ---- stage weights (once per block), packed bf16, transposed ----
    for (int n = tid; n < 544*18; n += BLK){
        int col = n / 18, p = n % 18, i = 2*p;
        unsigned lo = (i   < 34) ? bf16b(Wup[i*544 + col])     : 0u;
        unsigned hi = (i+1 < 34) ? bf16b(Wup[(i+1)*544 + col]) : 0u;
        s_wup[n] = lo | (hi << 16);
    }
    for (int n = tid; n < 32*33; n += BLK){
        int hh = n / 33, p = n % 33;
        unsigned v = 0u;
        if (p < 32) v = bf16b(Wud[(2*p)*32 + hh]) | (bf16b(Wud[(2*p+1)*32 + hh]) << 16);
        s_wud[n] = v;
    }
    for (int n = tid; n < 32*17; n += BLK){
        int hh = n / 17, p = n % 17;
        if (p < 16){
            int c0 = 2*p, c1 = 2*p+1;
            s_wq [n] = bf16b(Wq [c0*32+hh]) | (bf16b(Wq [c1*32+hh]) << 16);
            s_wk [n] = bf16b(Wk [c0*32+hh]) | (bf16b(Wk [c1*32+hh]) << 16);
            s_wv [n] = bf16b(Wv [c0*32+hh]) | (bf16b(Wv [c1*32+hh]) << 16);
            s_wd1[n] = bf16b(Wd1[c0*32+hh]) | (bf16b(Wd1[c1*32+hh]) << 16);
            s_wd2[n] = bf16b(Wd2[c0*32+hh]) | (bf16b(Wd2[c1*32+hh]) << 16);
        } else {
            s_wq[n]=0u; s_wk[n]=0u; s_wv[n]=0u; s_wd1[n]=0u; s_wd2[n]=0u;
        }
    }
    for (int n = tid; n < 544; n += BLK) s_bup[n] = bup[n];
    if (tid < 32){
        s_bud[tid]=bud[tid]; s_bq[tid]=bq[tid]; s_bk[tid]=bk[tid]; s_bv[tid]=bv[tid];
        s_bd1[tid]=bd1[tid]; s_bd2[tid]=bd2[tid]; s_ws[tid]=Ws[tid];
    }
    if (tid == 0){
        // Detect mask encoding: int32 (0/1), uint8 bool, or float32. With exactly
        // 9-of-17 True per sample these byte patterns are mutually exclusive in
        // the first 68 bytes.
        const unsigned char* mb = (const unsigned char*)mraw;
        bool f3f=false, nz=false;
        for (int i=0;i<68;i++){
            unsigned char c = mb[i];
            if ((i&3)==3 && c==0x3Fu) f3f = true;
            if ((i&3)!=0 && c!=0)     nz  = true;
        }
        s_mode = f3f ? 2 : (nz ? 1 : 0);
    }
    __syncthreads();
    // positions @ W_ud[32:64] — sample-independent, precompute once per block
    for (int n = tid; n < 544; n += BLK){
        int j = n / 32, hh = n % 32;
        float acc = 0.f;
        for (int p=0;p<16;p++){
            unsigned u = s_wud[hh*33 + 16 + p];
            acc += pos[j*32 + 2*p]*lo16(u) + pos[j*32 + 2*p + 1]*hi16(u);
        }
        s_pp[j*33+hh] = acc;
    }

    const int sid = tid >> 5, h = tid & 31;
    const float bsv = bs[0];
    const int ntiles = (B + SB - 1) / SB;

    for (int tile = blockIdx.x; tile < ntiles; tile += gridDim.x){
        __syncthreads();
        for (int n = tid; n < SB*34; n += BLK){
            int ss = n / 34, ii = n % 34;
            int smp = tile*SB + ss;
            s_xs[ss*36+ii] = (smp < B) ? x[(size_t)smp*34 + ii] : 0.f;
        }
        if (h == 0 && tile*SB + sid < B){
            size_t base = (size_t)(tile*SB + sid) * JN;
            int mode = s_mode, a = 0, b = NTV;
            for (int j=0;j<JN;j++){
                bool t;
                if (mode == 0)      t = ((const int*)mraw)[base+j] != 0;
                else if (mode == 1) t = ((const unsigned char*)mraw)[base+j] != 0;
                else                t = ((const float*)mraw)[base+j] != 0.f;
                if (t) s_perm[sid*20 + (a++)] = j;   // visible, increasing
                else   s_perm[sid*20 + (b++)] = j;   // occluded, increasing
            }
        }
        __syncthreads();

        int pj[JN];
        #pragma unroll
        for (int r=0;r<JN;r++) pj[r] = s_perm[sid*20+r];

        // ---- up = leaky(x @ W_up + b_up), rows permuted ----
        float up[JN];
        #pragma unroll
        for (int r=0;r<JN;r++) up[r] = s_bup[pj[r]*32 + h];
        const float2* xs2 = (const float2*)&s_xs[sid*36];
        #pragma unroll 1
        for (int p=0;p<17;p++){
            float2 xv = xs2[p];
            #pragma unroll
            for (int r=0;r<JN;r++){
                unsigned u = s_wup[(pj[r]*32+h)*18 + p];
                up[r] += xv.x*lo16(u) + xv.y*hi16(u);
            }
        }
        #pragma unroll
        for (int r=0;r<JN;r++) up[r] = lrelu(up[r]);

        // ---- u = leaky(b_ud + pospart[joint] + up @ W_ud[0:32]) ----
        float uu[JN];
        #pragma unroll
        for (int r=0;r<JN;r++) uu[r] = s_bud[h] + s_pp[pj[r]*33 + h];
        #pragma unroll 1
        for (int p=0;p<16;p++){
            unsigned w = s_wud[h*33+p];
            float wl = lo16(w), wh = hi16(w);
            #pragma unroll
            for (int r=0;r<JN;r++){
                float a = __shfl(up[r], 2*p,   32);
                float b = __shfl(up[r], 2*p+1, 32);
                uu[r] += a*wl + b*wh;
            }
        }
        #pragma unroll
        for (int r=0;r<JN;r++) uu[r] = lrelu(uu[r]);

        // ---- q (rows 9..16), k, v (all rows) ----
        float kk[JN], vv[JN], qq[8];
        #pragma unroll
        for (int r=0;r<JN;r++){ kk[r]=s_bk[h]; vv[r]=s_bv[h]; }
        #pragma unroll
        for (int i=0;i<8;i++) qq[i]=s_bq[h];
        #pragma unroll 1
        for (int p=0;p<16;p++){
            unsigned wk_=s_wk[h*17+p], wv_=s_wv[h*17+p], wq_=s_wq[h*17+p];
            float kl=lo16(wk_), kh=hi16(wk_), vl=lo16(wv_), vh=hi16(wv_), ql=lo16(wq_), qh=hi16(wq_);
            #pragma unroll
            for (int r=0;r<JN;r++){
                float a = __shfl(uu[r], 2*p,   32);
                float b = __shfl(uu[r], 2*p+1, 32);
                kk[r] += a*kl + b*kh;
                vv[r] += a*vl + b*vh;
                if (r >= NTV) qq[r-NTV] += a*ql + b*qh;
            }
        }
        #pragma unroll
        for (int i=0;i<8;i++) qq[i] *= 0.17677669529663687f;  // 1/sqrt(32)

        // ---- scores + softmax (butterfly reductions over 32 lanes) ----
        float att[8];
        #pragma unroll
        for (int qi=0; qi<8; qi++){
            float av = -1e30f;
            #pragma unroll
            for (int kj=0;kj<JN;kj++){
                float pr = qq[qi]*kk[kj];
                pr += __shfl_xor(pr, 1, 32);
                pr += __shfl_xor(pr, 2, 32);
                pr += __shfl_xor(pr, 4, 32);
                pr += __shfl_xor(pr, 8, 32);
                pr += __shfl_xor(pr,16, 32);
                if (h == kj) av = pr;   // lane kj keeps score for key kj
            }
            float mv = (h < JN) ? av : -1e30f;
            mv = fmaxf(mv, __shfl_xor(mv, 1, 32));
            mv = fmaxf(mv, __shfl_xor(mv, 2, 32));
            mv = fmaxf(mv, __shfl_xor(mv, 4, 32));
            mv = fmaxf(mv, __shfl_xor(mv, 8, 32));
            mv = fmaxf(mv, __shfl_xor(mv,16, 32));
            float e = __expf(av - mv);
            e = (h < JN) ? e : 0.f;
            float sm = e;
            sm += __shfl_xor(sm, 1, 32);
            sm += __shfl_xor(sm, 2, 32);
            sm += __shfl_xor(sm, 4, 32);
            sm += __shfl_xor(sm, 8, 32);
            sm += __shfl_xor(sm,16, 32);
            att[qi] = e / sm;
        }

        // ---- o = att @ v ----
        float oo[8];
        #pragma unroll
        for (int qi=0;qi<8;qi++){
            float acc = 0.f;
            #pragma unroll
            for (int kj=0;kj<JN;kj++) acc += __shfl(att[qi], kj, 32) * vv[kj];
            oo[qi] = acc;
        }

        // ---- d1 ----
        float tt[8];
        #pragma unroll
        for (int qi=0;qi<8;qi++) tt[qi] = s_bd1[h];
        #pragma unroll 1
        for (int p=0;p<16;p++){
            unsigned w = s_wd1[h*17+p];
            float wl=lo16(w), wh=hi16(w);
            #pragma unroll
            for (int qi=0;qi<8;qi++){
                float a = __shfl(oo[qi], 2*p,   32);
                float b = __shfl(oo[qi], 2*p+1, 32);
                tt[qi] += a*wl + b*wh;
            }
        }
        #pragma unroll
        for (int qi=0;qi<8;qi++) tt[qi] = lrelu(tt[qi]);

        // ---- d2 + residual (x2 = permuted up rows 9..16) ----
        float zz[8];
        #pragma unroll
        for (int qi=0;qi<8;qi++) zz[qi] = s_bd2[h] + up[NTV+qi];
        #pragma unroll 1
        for (int p=0;p<16;p++){
            unsigned w = s_wd2[h*17+p];
            float wl=lo16(w), wh=hi16(w);
            #pragma unroll
            for (int qi=0;qi<8;qi++){
                float a = __shfl(tt[qi], 2*p,   32);
                float b = __shfl(tt[qi], 2*p+1, 32);
                zz[qi] += a*wl + b*wh;
            }
        }

        // ---- sigmoid(z @ W_s + b_s) ----
        float val = 0.f;
        #pragma unroll
        for (int qi=0;qi<8;qi++){
            float pr = zz[qi] * s_ws[h];
            pr += __shfl_xor(pr, 1, 32);
            pr += __shfl_xor(pr, 2, 32);
            pr += __shfl_xor(pr, 4, 32);
            pr += __shfl_xor(pr, 8, 32);
            pr += __shfl_xor(pr,16, 32);
            float y = pr + bsv;
            float sg = 1.f / (1.f + __expf(-y));
            if (h == qi) val = sg;
        }
        int smp = tile*SB + sid;
        if (h < 8 && smp < B) out[(size_t)smp*8 + h] = val;
    }
}

extern "C" void kernel_launch(void* const* d_in, const int* in_sizes, int n_in,
                              void* d_out, int out_size, void* d_ws, size_t ws_size,
                              hipStream_t stream) {
    (void)n_in; (void)d_ws; (void)ws_size; (void)out_size;
    const float* x   = (const float*)d_in[0];
    const void*  m   = d_in[1];
    const float* pos = (const float*)d_in[2];
    const float* Wup = (const float*)d_in[3];  const float* bup = (const float*)d_in[4];
    const float* Wud = (const float*)d_in[5];  const float* bud = (const float*)d_in[6];
    const float* Wq  = (const float*)d_in[7];  const float* bq  = (const float*)d_in[8];
    const float* Wk  = (const float*)d_in[9];  const float* bk  = (const float*)d_in[10];
    const float* Wv  = (const float*)d_in[11]; const float* bv  = (const float*)d_in[12];
    const float* Wd1 = (const float*)d_in[13]; const float* bd1 = (const float*)d_in[14];
    const float* Wd2 = (const float*)d_in[15]; const float* bd2 = (const float*)d_in[16];
    const float* Ws  = (const float*)d_in[17]; const float* bs  = (const float*)d_in[18];
    int B = in_sizes[0] / (JN*2);
    dim3 grid(512), block(BLK);
    hipLaunchKernelGGL(score_kernel, grid, block, 0, stream,
                       x, m, pos, Wup, bup, Wud, bud, Wq, bq, Wk, bk,
                       Wv, bv, Wd1, bd1, Wd2, bd2, Ws, bs, (float*)d_out, B);
}

// Round 2
// 529.450 us; speedup vs baseline: 1.9488x; 1.9488x over previous
//
#include <hip/hip_runtime.h>
#include <hip/hip_bf16.h>

#define JN 17
#define NTV 9

__device__ __forceinline__ float lo16(unsigned u){ return __uint_as_float(u << 16); }
__device__ __forceinline__ float hi16(unsigned u){ return __uint_as_float(u & 0xFFFF0000u); }
__device__ __forceinline__ float lrelu(float x){ return fmaxf(x, 0.01f*x); }
__device__ __forceinline__ unsigned pk2(float lo, float hi){
    unsigned r; asm("v_cvt_pk_bf16_f32 %0, %1, %2" : "=v"(r) : "v"(lo), "v"(hi)); return r;
}

// ---------------- prep: mask -> bitmask, pp = bud + positions @ Wud[32:64] ----
__global__ __launch_bounds__(256,1)
void prep_kernel(const void* __restrict__ mraw, const float* __restrict__ pos,
                 const float* __restrict__ Wud, const float* __restrict__ bud,
                 float* __restrict__ pp, unsigned* __restrict__ bmask, int B)
{
    int g = blockIdx.x*256 + threadIdx.x;
    // mode detection from first 68 bytes (exclusive patterns; see round-1 notes)
    const unsigned* mw = (const unsigned*)mraw;
    bool f3f=false, nz=false;
    #pragma unroll
    for (int i=0;i<17;i++){
        unsigned w = mw[i];
        if ((w>>24) == 0x3Fu) f3f = true;
        if (w & 0xFFFFFF00u)  nz  = true;
    }
    int mode = f3f ? 2 : (nz ? 1 : 0);
    if (g < B){
        unsigned bm = 0; size_t base = (size_t)g*JN;
        if (mode == 0){
            const int* mi = (const int*)mraw;
            #pragma unroll
            for (int j=0;j<JN;j++) if (mi[base+j] != 0) bm |= (1u<<j);
        } else if (mode == 1){
            const unsigned char* mb = (const unsigned char*)mraw;
            #pragma unroll
            for (int j=0;j<JN;j++) if (mb[base+j] != 0) bm |= (1u<<j);
        } else {
            const float* mf = (const float*)mraw;
            #pragma unroll
            for (int j=0;j<JN;j++) if (mf[base+j] != 0.f) bm |= (1u<<j);
        }
        bmask[g] = bm;
    }
    if (g < 544){
        int j = g >> 5, h = g & 31;
        float acc = bud[h];
        #pragma unroll
        for (int c=0;c<32;c++) acc = fmaf(pos[j*32+c], Wud[(32+c)*32 + h], acc);
        pp[g] = acc;
    }
}

// ---------------- pass 1: per-lane sample; up/uu/k/v; write bf16 to ws -------
__global__ __launch_bounds__(256,1)
void pass1_kernel(const float* __restrict__ x, const unsigned* __restrict__ bmask,
                  const float* __restrict__ pp,
                  const float* __restrict__ Wup, const float* __restrict__ bup,
                  const float* __restrict__ Wud,
                  const float* __restrict__ Wk, const float* __restrict__ bk,
                  const float* __restrict__ Wv, const float* __restrict__ bv,
                  unsigned* __restrict__ ku, unsigned* __restrict__ vu,
                  unsigned* __restrict__ uuo, unsigned* __restrict__ upo,
                  int start, int n)
{
    int li = blockIdx.x*256 + threadIdx.x;
    bool act = li < n;
    int s = start + (act ? li : 0);
    size_t ss = (size_t)(act ? li : 0);

    float xr[34];
    const float2* xp = (const float2*)(x + (size_t)s*34);
    #pragma unroll
    for (int i=0;i<17;i++){ float2 t = xp[i]; xr[2*i]=t.x; xr[2*i+1]=t.y; }
    unsigned bm = bmask[s];

    #pragma unroll 1
    for (int j=0;j<JN;j++){
        bool occ = act && !((bm>>j)&1u);
        int rk = __popc((~bm) & ((1u<<j)-1u));

        // up row (fp32, weights via uniform s_load)
        float up[32];
        #pragma unroll
        for (int h=0;h<32;h++) up[h] = bup[j*32+h];
        #pragma unroll
        for (int c=0;c<34;c++){
            float xv = xr[c];
            #pragma unroll
            for (int h=0;h<32;h++) up[h] = fmaf(xv, Wup[c*544 + j*32 + h], up[h]);
        }
        #pragma unroll
        for (int h=0;h<32;h++) up[h] = lrelu(up[h]);

        if (occ){   // residual row (x2) for pass 2
            unsigned t[16];
            #pragma unroll
            for (int p=0;p<16;p++) t[p] = pk2(up[2*p], up[2*p+1]);
            uint4* d = (uint4*)(upo + (ss*8 + rk)*16);
            d[0] = make_uint4(t[0],t[1],t[2],t[3]);
            d[1] = make_uint4(t[4],t[5],t[6],t[7]);
            d[2] = make_uint4(t[8],t[9],t[10],t[11]);
            d[3] = make_uint4(t[12],t[13],t[14],t[15]);
        }

        // uu row
        float uu[32];
        #pragma unroll
        for (int h=0;h<32;h++) uu[h] = pp[j*32+h];
        #pragma unroll
        for (int c=0;c<32;c++){
            float a = up[c];
            #pragma unroll
            for (int h=0;h<32;h++) uu[h] = fmaf(a, Wud[c*32+h], uu[h]);
        }
        #pragma unroll
        for (int h=0;h<32;h++) uu[h] = lrelu(uu[h]);

        if (occ){   // uu row for q-computation in pass 2
            unsigned t[16];
            #pragma unroll
            for (int p=0;p<16;p++) t[p] = pk2(uu[2*p], uu[2*p+1]);
            uint4* d = (uint4*)(uuo + (ss*8 + rk)*16);
            d[0] = make_uint4(t[0],t[1],t[2],t[3]);
            d[1] = make_uint4(t[4],t[5],t[6],t[7]);
            d[2] = make_uint4(t[8],t[9],t[10],t[11]);
            d[3] = make_uint4(t[12],t[13],t[14],t[15]);
        }

        // k and v rows
        float ka[32], va[32];
        #pragma unroll
        for (int h=0;h<32;h++){ ka[h]=bk[h]; va[h]=bv[h]; }
        #pragma unroll
        for (int c=0;c<32;c++){
            float a = uu[c];
            #pragma unroll
            for (int h=0;h<32;h++){
                ka[h] = fmaf(a, Wk[c*32+h], ka[h]);
                va[h] = fmaf(a, Wv[c*32+h], va[h]);
            }
        }
        if (act){
            unsigned t[16];
            #pragma unroll
            for (int p=0;p<16;p++) t[p] = pk2(ka[2*p], ka[2*p+1]);
            uint4* kd = (uint4*)(ku + (ss*JN + j)*16);
            kd[0] = make_uint4(t[0],t[1],t[2],t[3]);
            kd[1] = make_uint4(t[4],t[5],t[6],t[7]);
            kd[2] = make_uint4(t[8],t[9],t[10],t[11]);
            kd[3] = make_uint4(t[12],t[13],t[14],t[15]);
            #pragma unroll
            for (int p=0;p<16;p++) t[p] = pk2(va[2*p], va[2*p+1]);
            uint4* vd = (uint4*)(vu + (ss*JN + j)*16);
            vd[0] = make_uint4(t[0],t[1],t[2],t[3]);
            vd[1] = make_uint4(t[4],t[5],t[6],t[7]);
            vd[2] = make_uint4(t[8],t[9],t[10],t[11]);
            vd[3] = make_uint4(t[12],t[13],t[14],t[15]);
        }
    }
}

// ---------------- pass 2: per-lane (sample, query): attention + head ---------
__global__ __launch_bounds__(256,4)
void pass2_kernel(const unsigned* __restrict__ ku, const unsigned* __restrict__ vu,
                  const unsigned* __restrict__ uuo, const unsigned* __restrict__ upo,
                  const float* __restrict__ Wq, const float* __restrict__ bq,
                  const float* __restrict__ Wd1, const float* __restrict__ bd1,
                  const float* __restrict__ Wd2, const float* __restrict__ bd2,
                  const float* __restrict__ Ws, const float* __restrict__ bs,
                  float* __restrict__ out, int start, int n)
{
    int g = blockIdx.x*256 + threadIdx.x;
    if (g >= n*8) return;
    int sl = g >> 3, qi = g & 7;

    // uu row -> q
    unsigned uw[16];
    {
        const uint4* p4 = (const uint4*)(uuo + ((size_t)sl*8 + qi)*16);
        uint4 a = p4[0], b = p4[1], c = p4[2], d = p4[3];
        uw[0]=a.x; uw[1]=a.y; uw[2]=a.z; uw[3]=a.w;
        uw[4]=b.x; uw[5]=b.y; uw[6]=b.z; uw[7]=b.w;
        uw[8]=c.x; uw[9]=c.y; uw[10]=c.z; uw[11]=c.w;
        uw[12]=d.x; uw[13]=d.y; uw[14]=d.z; uw[15]=d.w;
    }
    float uur[32];
    #pragma unroll
    for (int p=0;p<16;p++){ uur[2*p]=lo16(uw[p]); uur[2*p+1]=hi16(uw[p]); }

    float q[32];
    #pragma unroll
    for (int h=0;h<32;h++) q[h] = bq[h];
    #pragma unroll
    for (int c=0;c<32;c++){
        float a = uur[c];
        #pragma unroll
        for (int h=0;h<32;h++) q[h] = fmaf(a, Wq[c*32+h], q[h]);
    }
    #pragma unroll
    for (int h=0;h<32;h++) q[h] *= 0.17677669529663687f;   // 1/sqrt(32)

    // scores vs all 17 keys (lane-local softmax row)
    float sc[JN];
    #pragma unroll
    for (int kj=0;kj<JN;kj++){
        const uint4* kp = (const uint4*)(ku + ((size_t)sl*JN + kj)*16);
        uint4 a = kp[0], b = kp[1], c = kp[2], d = kp[3];
        unsigned kw[16] = {a.x,a.y,a.z,a.w,b.x,b.y,b.z,b.w,c.x,c.y,c.z,c.w,d.x,d.y,d.z,d.w};
        float a0=0.f,a1=0.f,a2=0.f,a3=0.f;
        #pragma unroll
        for (int p=0;p<16;p++){
            float l = lo16(kw[p]), h = hi16(kw[p]);
            if ((p&1)==0){ a0 = fmaf(q[2*p], l, a0); a1 = fmaf(q[2*p+1], h, a1); }
            else         { a2 = fmaf(q[2*p], l, a2); a3 = fmaf(q[2*p+1], h, a3); }
        }
        sc[kj] = (a0+a1)+(a2+a3);
    }
    float m = sc[0];
    #pragma unroll
    for (int kj=1;kj<JN;kj++) m = fmaxf(m, sc[kj]);
    float e[JN]; float sum = 0.f;
    #pragma unroll
    for (int kj=0;kj<JN;kj++){ e[kj] = __expf(sc[kj]-m); sum += e[kj]; }
    float ri = 1.0f/sum;

    // o = att @ v
    float o[32];
    #pragma unroll
    for (int h=0;h<32;h++) o[h] = 0.f;
    #pragma unroll
    for (int kj=0;kj<JN;kj++){
        float w = e[kj]*ri;
        const uint4* vp = (const uint4*)(vu + ((size_t)sl*JN + kj)*16);
        uint4 a = vp[0], b = vp[1], c = vp[2], d = vp[3];
        unsigned vw[16] = {a.x,a.y,a.z,a.w,b.x,b.y,b.z,b.w,c.x,c.y,c.z,c.w,d.x,d.y,d.z,d.w};
        #pragma unroll
        for (int p=0;p<16;p++){
            o[2*p]   = fmaf(w, lo16(vw[p]), o[2*p]);
            o[2*p+1] = fmaf(w, hi16(vw[p]), o[2*p+1]);
        }
    }

    // d1
    float t[32];
    #pragma unroll
    for (int h=0;h<32;h++) t[h] = bd1[h];
    #pragma unroll
    for (int c=0;c<32;c++){
        float a = o[c];
        #pragma unroll
        for (int h=0;h<32;h++) t[h] = fmaf(a, Wd1[c*32+h], t[h]);
    }
    #pragma unroll
    for (int h=0;h<32;h++) t[h] = lrelu(t[h]);

    // d2 + residual
    float z[32];
    {
        const uint4* p4 = (const uint4*)(upo + ((size_t)sl*8 + qi)*16);
        uint4 a = p4[0], b = p4[1], c = p4[2], d = p4[3];
        unsigned pw[16] = {a.x,a.y,a.z,a.w,b.x,b.y,b.z,b.w,c.x,c.y,c.z,c.w,d.x,d.y,d.z,d.w};
        #pragma unroll
        for (int p=0;p<16;p++){ z[2*p] = bd2[2*p] + lo16(pw[p]); z[2*p+1] = bd2[2*p+1] + hi16(pw[p]); }
    }
    #pragma unroll
    for (int c=0;c<32;c++){
        float a = t[c];
        #pragma unroll
        for (int h=0;h<32;h++) z[h] = fmaf(a, Wd2[c*32+h], z[h]);
    }

    // sigmoid(z @ Ws + bs)
    float y0=0.f, y1=0.f;
    #pragma unroll
    for (int h=0;h<32;h+=2){ y0 = fmaf(z[h], Ws[h], y0); y1 = fmaf(z[h+1], Ws[h+1], y1); }
    float y = y0 + y1 + bs[0];
    out[((size_t)(start + sl))*8 + qi] = 1.0f/(1.0f + __expf(-y));
}

extern "C" void kernel_launch(void* const* d_in, const int* in_sizes, int n_in,
                              void* d_out, int out_size, void* d_ws, size_t ws_size,
                              hipStream_t stream) {
    (void)n_in; (void)out_size;
    const float* x   = (const float*)d_in[0];
    const void*  m   = d_in[1];
    const float* pos = (const float*)d_in[2];
    const float* Wup = (const float*)d_in[3];  const float* bup = (const float*)d_in[4];
    const float* Wud = (const float*)d_in[5];  const float* bud = (const float*)d_in[6];
    const float* Wq  = (const float*)d_in[7];  const float* bq  = (const float*)d_in[8];
    const float* Wk  = (const float*)d_in[9];  const float* bk  = (const float*)d_in[10];
    const float* Wv  = (const float*)d_in[11]; const float* bv  = (const float*)d_in[12];
    const float* Wd1 = (const float*)d_in[13]; const float* bd1 = (const float*)d_in[14];
    const float* Wd2 = (const float*)d_in[15]; const float* bd2 = (const float*)d_in[16];
    const float* Ws  = (const float*)d_in[17]; const float* bs  = (const float*)d_in[18];
    float* out = (float*)d_out;
    int B = in_sizes[0] / (JN*2);

    unsigned char* wsb = (unsigned char*)d_ws;
    float*    pp    = (float*)(wsb + 0);                       // 544 f32
    unsigned* bmask = (unsigned*)(wsb + 4096);                 // B u32
    size_t data_off = (4096 + (size_t)B*4 + 255) & ~(size_t)255;
    // per-sample ws: k 272 u32, v 272, uuo 128, upo 128  => 800 u32 = 3200 B
    long cap = 0;
    if (ws_size > data_off) cap = (long)((ws_size - data_off) / 3200);
    cap = (cap/64)*64;
    if (cap <= 0) return;                 // workspace unusably small
    if (cap > B) cap = (long)B;
    unsigned* ku  = (unsigned*)(wsb + data_off);
    unsigned* vu  = ku  + (size_t)cap*272;
    unsigned* uuo = ku  + (size_t)cap*544;
    unsigned* upo = ku  + (size_t)cap*672;

    prep_kernel<<<(B+255)/256, 256, 0, stream>>>(m, pos, Wud, bud, pp, bmask, B);
    for (long start = 0; start < B; start += cap){
        int n = (int)((B - start < cap) ? (B - start) : cap);
        pass1_kernel<<<(n+255)/256, 256, 0, stream>>>(x, bmask, pp, Wup, bup, Wud,
                                                      Wk, bk, Wv, bv, ku, vu, uuo, upo,
                                                      (int)start, n);
        pass2_kernel<<<(n*8+255)/256, 256, 0, stream>>>(ku, vu, uuo, upo, Wq, bq,
                                                        Wd1, bd1, Wd2, bd2, Ws, bs,
                                                        out, (int)start, n);
    }
}

// Round 3
// 361.861 us; speedup vs baseline: 2.8513x; 1.4631x over previous
//
#include <hip/hip_runtime.h>
#include <hip/hip_bf16.h>

#define JN 17
#define NTV 9

__device__ __forceinline__ float lo16(unsigned u){ return __uint_as_float(u << 16); }
__device__ __forceinline__ float hi16(unsigned u){ return __uint_as_float(u & 0xFFFF0000u); }
__device__ __forceinline__ float lrelu(float x){ return fmaxf(x, 0.01f*x); }
__device__ __forceinline__ unsigned pk2(float lo, float hi){
    unsigned r; asm("v_cvt_pk_bf16_f32 %0, %1, %2" : "=v"(r) : "v"(lo), "v"(hi)); return r;
}

// ---------------- prep: mask -> bitmask, pp = bud + positions @ Wud[32:64] ----
__global__ __launch_bounds__(256,1)
void prep_kernel(const void* __restrict__ mraw, const float* __restrict__ pos,
                 const float* __restrict__ Wud, const float* __restrict__ bud,
                 float* __restrict__ pp, unsigned* __restrict__ bmask, int B)
{
    int g = blockIdx.x*256 + threadIdx.x;
    // mode detection from first 68 bytes (encodings mutually exclusive given 9-of-17 True)
    const unsigned* mw = (const unsigned*)mraw;
    bool f3f=false, nz=false;
    #pragma unroll
    for (int i=0;i<17;i++){
        unsigned w = mw[i];
        if ((w>>24) == 0x3Fu) f3f = true;
        if (w & 0xFFFFFF00u)  nz  = true;
    }
    int mode = f3f ? 2 : (nz ? 1 : 0);
    if (g < B){
        unsigned bm = 0; size_t base = (size_t)g*JN;
        if (mode == 0){
            const int* mi = (const int*)mraw;
            #pragma unroll
            for (int j=0;j<JN;j++) if (mi[base+j] != 0) bm |= (1u<<j);
        } else if (mode == 1){
            const unsigned char* mb = (const unsigned char*)mraw;
            #pragma unroll
            for (int j=0;j<JN;j++) if (mb[base+j] != 0) bm |= (1u<<j);
        } else {
            const float* mf = (const float*)mraw;
            #pragma unroll
            for (int j=0;j<JN;j++) if (mf[base+j] != 0.f) bm |= (1u<<j);
        }
        bmask[g] = bm;
    }
    if (g < 544){
        int j = g >> 5, h = g & 31;
        float acc = bud[h];
        #pragma unroll
        for (int c=0;c<32;c++) acc = fmaf(pos[j*32+c], Wud[(32+c)*32 + h], acc);
        pp[g] = acc;
    }
}

// ---------------- pass 1: one lane per (sample, joint); j = blockIdx.y -------
// Weights indexed uniformly per block -> scalar loads. ku/vu laid out j-major
// [17][cap][16 u32] so per-block writes are lane-contiguous (coalesced).
__global__ __launch_bounds__(256,4)
void pass1_kernel(const float* __restrict__ x, const unsigned* __restrict__ bmask,
                  const float* __restrict__ pp,
                  const float* __restrict__ Wup, const float* __restrict__ bup,
                  const float* __restrict__ Wud,
                  const float* __restrict__ Wk, const float* __restrict__ bk,
                  const float* __restrict__ Wv, const float* __restrict__ bv,
                  unsigned* __restrict__ ku, unsigned* __restrict__ vu,
                  unsigned* __restrict__ uuo, unsigned* __restrict__ upo,
                  int start, int n, long cap)
{
    int li = blockIdx.x*256 + threadIdx.x;
    if (li >= n) return;
    const int j = blockIdx.y;
    const int s = start + li;

    float xr[34];
    const float2* xp = (const float2*)(x + (size_t)s*34);
    #pragma unroll
    for (int i=0;i<17;i++){ float2 t = xp[i]; xr[2*i]=t.x; xr[2*i+1]=t.y; }
    const unsigned bm = bmask[s];
    const bool occ = !((bm>>j)&1u);
    const int rk = __popc((~bm) & ((1u<<j)-1u));

    // up row
    float up[32];
    #pragma unroll
    for (int h=0;h<32;h++) up[h] = bup[j*32+h];
    #pragma unroll
    for (int c=0;c<34;c++){
        float xv = xr[c];
        #pragma unroll
        for (int h=0;h<32;h++) up[h] = fmaf(xv, Wup[c*544 + j*32 + h], up[h]);
    }
    #pragma unroll
    for (int h=0;h<32;h++) up[h] = lrelu(up[h]);

    if (occ){   // residual row (x2) for pass 2, sample-major [cap][8][16]
        unsigned t[16];
        #pragma unroll
        for (int p=0;p<16;p++) t[p] = pk2(up[2*p], up[2*p+1]);
        uint4* d = (uint4*)(upo + ((size_t)li*8 + rk)*16);
        d[0] = make_uint4(t[0],t[1],t[2],t[3]);
        d[1] = make_uint4(t[4],t[5],t[6],t[7]);
        d[2] = make_uint4(t[8],t[9],t[10],t[11]);
        d[3] = make_uint4(t[12],t[13],t[14],t[15]);
    }

    // uu row
    float uu[32];
    #pragma unroll
    for (int h=0;h<32;h++) uu[h] = pp[j*32+h];
    #pragma unroll
    for (int c=0;c<32;c++){
        float a = up[c];
        #pragma unroll
        for (int h=0;h<32;h++) uu[h] = fmaf(a, Wud[c*32+h], uu[h]);
    }
    #pragma unroll
    for (int h=0;h<32;h++) uu[h] = lrelu(uu[h]);

    if (occ){
        unsigned t[16];
        #pragma unroll
        for (int p=0;p<16;p++) t[p] = pk2(uu[2*p], uu[2*p+1]);
        uint4* d = (uint4*)(uuo + ((size_t)li*8 + rk)*16);
        d[0] = make_uint4(t[0],t[1],t[2],t[3]);
        d[1] = make_uint4(t[4],t[5],t[6],t[7]);
        d[2] = make_uint4(t[8],t[9],t[10],t[11]);
        d[3] = make_uint4(t[12],t[13],t[14],t[15]);
    }

    // k row, then v row (re-use accumulator regs)
    {
        float acc[32];
        #pragma unroll
        for (int h=0;h<32;h++) acc[h] = bk[h];
        #pragma unroll
        for (int c=0;c<32;c++){
            float a = uu[c];
            #pragma unroll
            for (int h=0;h<32;h++) acc[h] = fmaf(a, Wk[c*32+h], acc[h]);
        }
        unsigned t[16];
        #pragma unroll
        for (int p=0;p<16;p++) t[p] = pk2(acc[2*p], acc[2*p+1]);
        uint4* d = (uint4*)(ku + ((size_t)j*cap + li)*16);
        d[0] = make_uint4(t[0],t[1],t[2],t[3]);
        d[1] = make_uint4(t[4],t[5],t[6],t[7]);
        d[2] = make_uint4(t[8],t[9],t[10],t[11]);
        d[3] = make_uint4(t[12],t[13],t[14],t[15]);
    }
    {
        float acc[32];
        #pragma unroll
        for (int h=0;h<32;h++) acc[h] = bv[h];
        #pragma unroll
        for (int c=0;c<32;c++){
            float a = uu[c];
            #pragma unroll
            for (int h=0;h<32;h++) acc[h] = fmaf(a, Wv[c*32+h], acc[h]);
        }
        unsigned t[16];
        #pragma unroll
        for (int p=0;p<16;p++) t[p] = pk2(acc[2*p], acc[2*p+1]);
        uint4* d = (uint4*)(vu + ((size_t)j*cap + li)*16);
        d[0] = make_uint4(t[0],t[1],t[2],t[3]);
        d[1] = make_uint4(t[4],t[5],t[6],t[7]);
        d[2] = make_uint4(t[8],t[9],t[10],t[11]);
        d[3] = make_uint4(t[12],t[13],t[14],t[15]);
    }
}

// ---------------- pass 2: per-lane (sample, query): attention + head ---------
__global__ __launch_bounds__(256,4)
void pass2_kernel(const unsigned* __restrict__ ku, const unsigned* __restrict__ vu,
                  const unsigned* __restrict__ uuo, const unsigned* __restrict__ upo,
                  const float* __restrict__ Wq, const float* __restrict__ bq,
                  const float* __restrict__ Wd1, const float* __restrict__ bd1,
                  const float* __restrict__ Wd2, const float* __restrict__ bd2,
                  const float* __restrict__ Ws, const float* __restrict__ bs,
                  float* __restrict__ out, int start, int n, long cap)
{
    int g = blockIdx.x*256 + threadIdx.x;
    if (g >= n*8) return;
    int sl = g >> 3, qi = g & 7;

    // uu row -> q
    float uur[32];
    {
        const uint4* p4 = (const uint4*)(uuo + ((size_t)sl*8 + qi)*16);
        uint4 a = p4[0], b = p4[1], c = p4[2], d = p4[3];
        unsigned uw[16] = {a.x,a.y,a.z,a.w,b.x,b.y,b.z,b.w,c.x,c.y,c.z,c.w,d.x,d.y,d.z,d.w};
        #pragma unroll
        for (int p=0;p<16;p++){ uur[2*p]=lo16(uw[p]); uur[2*p+1]=hi16(uw[p]); }
    }

    float q[32];
    #pragma unroll
    for (int h=0;h<32;h++) q[h] = bq[h];
    #pragma unroll
    for (int c=0;c<32;c++){
        float a = uur[c];
        #pragma unroll
        for (int h=0;h<32;h++) q[h] = fmaf(a, Wq[c*32+h], q[h]);
    }
    #pragma unroll
    for (int h=0;h<32;h++) q[h] *= 0.17677669529663687f;   // 1/sqrt(32)

    // scores vs all 17 keys (lane-local softmax row); k is [17][cap][16u32]
    float sc[JN];
    #pragma unroll
    for (int kj=0;kj<JN;kj++){
        const uint4* kp = (const uint4*)(ku + ((size_t)kj*cap + sl)*16);
        uint4 a = kp[0], b = kp[1], c = kp[2], d = kp[3];
        unsigned kw[16] = {a.x,a.y,a.z,a.w,b.x,b.y,b.z,b.w,c.x,c.y,c.z,c.w,d.x,d.y,d.z,d.w};
        float a0=0.f,a1=0.f,a2=0.f,a3=0.f;
        #pragma unroll
        for (int p=0;p<16;p++){
            float l = lo16(kw[p]), h = hi16(kw[p]);
            if ((p&1)==0){ a0 = fmaf(q[2*p], l, a0); a1 = fmaf(q[2*p+1], h, a1); }
            else         { a2 = fmaf(q[2*p], l, a2); a3 = fmaf(q[2*p+1], h, a3); }
        }
        sc[kj] = (a0+a1)+(a2+a3);
    }
    float m = sc[0];
    #pragma unroll
    for (int kj=1;kj<JN;kj++) m = fmaxf(m, sc[kj]);
    float e[JN]; float sum = 0.f;
    #pragma unroll
    for (int kj=0;kj<JN;kj++){ e[kj] = __expf(sc[kj]-m); sum += e[kj]; }
    float ri = 1.0f/sum;

    // o = att @ v
    float o[32];
    #pragma unroll
    for (int h=0;h<32;h++) o[h] = 0.f;
    #pragma unroll
    for (int kj=0;kj<JN;kj++){
        float w = e[kj]*ri;
        const uint4* vp = (const uint4*)(vu + ((size_t)kj*cap + sl)*16);
        uint4 a = vp[0], b = vp[1], c = vp[2], d = vp[3];
        unsigned vw[16] = {a.x,a.y,a.z,a.w,b.x,b.y,b.z,b.w,c.x,c.y,c.z,c.w,d.x,d.y,d.z,d.w};
        #pragma unroll
        for (int p=0;p<16;p++){
            o[2*p]   = fmaf(w, lo16(vw[p]), o[2*p]);
            o[2*p+1] = fmaf(w, hi16(vw[p]), o[2*p+1]);
        }
    }

    // d1
    float t[32];
    #pragma unroll
    for (int h=0;h<32;h++) t[h] = bd1[h];
    #pragma unroll
    for (int c=0;c<32;c++){
        float a = o[c];
        #pragma unroll
        for (int h=0;h<32;h++) t[h] = fmaf(a, Wd1[c*32+h], t[h]);
    }
    #pragma unroll
    for (int h=0;h<32;h++) t[h] = lrelu(t[h]);

    // d2 + residual
    float z[32];
    {
        const uint4* p4 = (const uint4*)(upo + ((size_t)sl*8 + qi)*16);
        uint4 a = p4[0], b = p4[1], c = p4[2], d = p4[3];
        unsigned pw[16] = {a.x,a.y,a.z,a.w,b.x,b.y,b.z,b.w,c.x,c.y,c.z,c.w,d.x,d.y,d.z,d.w};
        #pragma unroll
        for (int p=0;p<16;p++){ z[2*p] = bd2[2*p] + lo16(pw[p]); z[2*p+1] = bd2[2*p+1] + hi16(pw[p]); }
    }
    #pragma unroll
    for (int c=0;c<32;c++){
        float a = t[c];
        #pragma unroll
        for (int h=0;h<32;h++) z[h] = fmaf(a, Wd2[c*32+h], z[h]);
    }

    // sigmoid(z @ Ws + bs)
    float y0=0.f, y1=0.f;
    #pragma unroll
    for (int h=0;h<32;h+=2){ y0 = fmaf(z[h], Ws[h], y0); y1 = fmaf(z[h+1], Ws[h+1], y1); }
    float y = y0 + y1 + bs[0];
    out[((size_t)(start + sl))*8 + qi] = 1.0f/(1.0f + __expf(-y));
}

extern "C" void kernel_launch(void* const* d_in, const int* in_sizes, int n_in,
                              void* d_out, int out_size, void* d_ws, size_t ws_size,
                              hipStream_t stream) {
    (void)n_in; (void)out_size;
    const float* x   = (const float*)d_in[0];
    const void*  m   = d_in[1];
    const float* pos = (const float*)d_in[2];
    const float* Wup = (const float*)d_in[3];  const float* bup = (const float*)d_in[4];
    const float* Wud = (const float*)d_in[5];  const float* bud = (const float*)d_in[6];
    const float* Wq  = (const float*)d_in[7];  const float* bq  = (const float*)d_in[8];
    const float* Wk  = (const float*)d_in[9];  const float* bk  = (const float*)d_in[10];
    const float* Wv  = (const float*)d_in[11]; const float* bv  = (const float*)d_in[12];
    const float* Wd1 = (const float*)d_in[13]; const float* bd1 = (const float*)d_in[14];
    const float* Wd2 = (const float*)d_in[15]; const float* bd2 = (const float*)d_in[16];
    const float* Ws  = (const float*)d_in[17]; const float* bs  = (const float*)d_in[18];
    float* out = (float*)d_out;
    int B = in_sizes[0] / (JN*2);

    unsigned char* wsb = (unsigned char*)d_ws;
    float*    pp    = (float*)(wsb + 0);                       // 544 f32
    unsigned* bmask = (unsigned*)(wsb + 4096);                 // B u32
    size_t data_off = (4096 + (size_t)B*4 + 255) & ~(size_t)255;
    // per-sample ws: k 272 u32, v 272, uuo 128, upo 128  => 800 u32 = 3200 B
    long cap = 0;
    if (ws_size > data_off) cap = (long)((ws_size - data_off) / 3200);
    cap = (cap/64)*64;
    if (cap <= 0) return;                 // workspace unusably small
    if (cap > B) cap = (long)B;
    unsigned* ku  = (unsigned*)(wsb + data_off);
    unsigned* vu  = ku  + (size_t)cap*272;
    unsigned* uuo = ku  + (size_t)cap*544;
    unsigned* upo = ku  + (size_t)cap*672;

    prep_kernel<<<(B+255)/256, 256, 0, stream>>>(m, pos, Wud, bud, pp, bmask, B);
    for (long start = 0; start < B; start += cap){
        int n = (int)((B - start < cap) ? (B - start) : cap);
        dim3 g1((n+255)/256, JN);
        pass1_kernel<<<g1, 256, 0, stream>>>(x, bmask, pp, Wup, bup, Wud,
                                             Wk, bk, Wv, bv, ku, vu, uuo, upo,
                                             (int)start, n, cap);
        pass2_kernel<<<(n*8+255)/256, 256, 0, stream>>>(ku, vu, uuo, upo, Wq, bq,
                                                        Wd1, bd1, Wd2, bd2, Ws, bs,
                                                        out, (int)start, n, cap);
    }
}

// Round 5
// 169.048 us; speedup vs baseline: 6.1036x; 2.1406x over previous
//
#include <hip/hip_runtime.h>
#include <hip/hip_bf16.h>
#include <hip/hip_fp16.h>

#define JN 17
#define NTV 9

typedef __fp16 h2v __attribute__((ext_vector_type(2)));

__device__ __forceinline__ float lrelu(float x){ return fmaxf(x, 0.01f*x); }
__device__ __forceinline__ unsigned h2u(h2v h){ unsigned u; __builtin_memcpy(&u, &h, 4); return u; }
__device__ __forceinline__ h2v u2h(unsigned u){ h2v h; __builtin_memcpy(&h, &u, 4); return h; }
__device__ __forceinline__ unsigned pkrtz(float a, float b){ return h2u(__builtin_amdgcn_cvt_pkrtz(a,b)); }
__device__ __forceinline__ float fdot2(unsigned a, unsigned b, float c){
    return __builtin_amdgcn_fdot2(u2h(a), u2h(b), c, false);
}
__device__ __forceinline__ unsigned pkfma(unsigned a, unsigned b, unsigned c){
    h2v r = u2h(a)*u2h(b) + u2h(c);     // compiles to v_pk_fma_f16
    return h2u(r);
}

// ws header layout (u32 units), header occupies first 65536 bytes
#define OFF_PP    0        // 544 f32  : bud + positions @ Wud[32:64]
#define OFF_BQS   544      // 32 f32   : bq * (1/sqrt(32))
#define OFF_WUD   576      // 512 u32  : Wud[0:32] f16 pairs (p,h)
#define OFF_WQ    1088     // 512 u32  : Wq * isq pairs
#define OFF_WK    1600
#define OFF_WV    2112
#define OFF_WD1   2624
#define OFF_WD2   3136
#define OFF_WUP   3648     // 9248 u32 : Wup pairs (j,p,h)
#define HDR_BYTES 65536

// ---------------- prep: bitmask + pack weights to f16 pairs ------------------
__global__ __launch_bounds__(256,1)
void prep_kernel(const void* __restrict__ mraw, const float* __restrict__ pos,
                 const float* __restrict__ Wup,
                 const float* __restrict__ Wud, const float* __restrict__ bud,
                 const float* __restrict__ Wq,  const float* __restrict__ bq,
                 const float* __restrict__ Wk,  const float* __restrict__ Wv,
                 const float* __restrict__ Wd1, const float* __restrict__ Wd2,
                 unsigned* __restrict__ ws32, unsigned* __restrict__ bmask, int B)
{
    int g = blockIdx.x*256 + threadIdx.x;
    const float isq = 0.17677669529663687f;  // 1/sqrt(32)

    // mask mode detection (encodings mutually exclusive given 9-of-17 True)
    const unsigned* mw = (const unsigned*)mraw;
    bool f3f=false, nz=false;
    #pragma unroll
    for (int i=0;i<17;i++){
        unsigned w = mw[i];
        if ((w>>24) == 0x3Fu) f3f = true;
        if (w & 0xFFFFFF00u)  nz  = true;
    }
    int mode = f3f ? 2 : (nz ? 1 : 0);
    if (g < B){
        unsigned bm = 0; size_t base = (size_t)g*JN;
        if (mode == 0){
            const int* mi = (const int*)mraw;
            #pragma unroll
            for (int j=0;j<JN;j++) if (mi[base+j] != 0) bm |= (1u<<j);
        } else if (mode == 1){
            const unsigned char* mb = (const unsigned char*)mraw;
            #pragma unroll
            for (int j=0;j<JN;j++) if (mb[base+j] != 0) bm |= (1u<<j);
        } else {
            const float* mf = (const float*)mraw;
            #pragma unroll
            for (int j=0;j<JN;j++) if (mf[base+j] != 0.f) bm |= (1u<<j);
        }
        bmask[g] = bm;
    }
    if (g < 544){
        int j = g >> 5, h = g & 31;
        float acc = bud[h];
        #pragma unroll
        for (int c=0;c<32;c++) acc = fmaf(pos[j*32+c], Wud[(32+c)*32 + h], acc);
        ((float*)ws32)[OFF_PP + g] = acc;
    }
    if (g < 32) ((float*)ws32)[OFF_BQS + g] = bq[g]*isq;
    if (g < 512){
        int p = g >> 5, h = g & 31;
        int c0 = 2*p, c1 = 2*p+1;
        ws32[OFF_WUD + g] = pkrtz(Wud[c0*32+h],      Wud[c1*32+h]);
        ws32[OFF_WQ  + g] = pkrtz(Wq [c0*32+h]*isq,  Wq [c1*32+h]*isq);
        ws32[OFF_WK  + g] = pkrtz(Wk [c0*32+h],      Wk [c1*32+h]);
        ws32[OFF_WV  + g] = pkrtz(Wv [c0*32+h],      Wv [c1*32+h]);
        ws32[OFF_WD1 + g] = pkrtz(Wd1[c0*32+h],      Wd1[c1*32+h]);
        ws32[OFF_WD2 + g] = pkrtz(Wd2[c0*32+h],      Wd2[c1*32+h]);
    }
    if (g < 9248){
        int h = g & 31, p = (g >> 5) % 17, j = g / (32*17);
        ws32[OFF_WUP + g] = pkrtz(Wup[(2*p)*544 + j*32 + h], Wup[(2*p+1)*544 + j*32 + h]);
    }
}

// ---------------- pass 1: one lane per (sample, joint); j = blockIdx.y -------
__global__ __launch_bounds__(256,4)
void pass1_kernel(const float* __restrict__ x, const unsigned* __restrict__ bmask,
                  const unsigned* __restrict__ ws32,
                  const float* __restrict__ bup,
                  const float* __restrict__ bk, const float* __restrict__ bv,
                  unsigned* __restrict__ ku, unsigned* __restrict__ vu,
                  unsigned* __restrict__ uuo, unsigned* __restrict__ upo,
                  int start, int n, long cap)
{
    int li = blockIdx.x*256 + threadIdx.x;
    if (li >= n) return;
    const int j = blockIdx.y;
    const int s = start + li;

    // pack x to 17 f16 pairs
    unsigned xp[17];
    const float2* xf = (const float2*)(x + (size_t)s*34);
    #pragma unroll
    for (int i=0;i<17;i++){ float2 t = xf[i]; xp[i] = pkrtz(t.x, t.y); }
    const unsigned bm = bmask[s];
    const bool occ = !((bm>>j)&1u);
    const int rk = __popc((~bm) & ((1u<<j)-1u));

    const unsigned* wup = ws32 + OFF_WUP + (size_t)j*17*32;
    const float*    pp  = (const float*)ws32 + OFF_PP + j*32;
    const unsigned* wud = ws32 + OFF_WUD;
    const unsigned* wk  = ws32 + OFF_WK;
    const unsigned* wv  = ws32 + OFF_WV;

    // up = leaky(x @ Wup_j + bup_j)
    float up[32];
    #pragma unroll
    for (int h=0;h<32;h++) up[h] = bup[j*32+h];
    #pragma unroll
    for (int p=0;p<17;p++){
        unsigned a = xp[p];
        #pragma unroll
        for (int h=0;h<32;h++) up[h] = fdot2(a, wup[p*32+h], up[h]);
    }
    unsigned upk[16];
    #pragma unroll
    for (int p=0;p<16;p++){ upk[p] = pkrtz(lrelu(up[2*p]), lrelu(up[2*p+1])); }

    if (occ){   // residual row (x2) for pass 2
        uint4* d = (uint4*)(upo + ((size_t)li*8 + rk)*16);
        d[0] = make_uint4(upk[0],upk[1],upk[2],upk[3]);
        d[1] = make_uint4(upk[4],upk[5],upk[6],upk[7]);
        d[2] = make_uint4(upk[8],upk[9],upk[10],upk[11]);
        d[3] = make_uint4(upk[12],upk[13],upk[14],upk[15]);
    }

    // uu = leaky(pp_j + up @ Wud0)
    float uu[32];
    #pragma unroll
    for (int h=0;h<32;h++) uu[h] = pp[h];
    #pragma unroll
    for (int p=0;p<16;p++){
        unsigned a = upk[p];
        #pragma unroll
        for (int h=0;h<32;h++) uu[h] = fdot2(a, wud[p*32+h], uu[h]);
    }
    unsigned uupk[16];
    #pragma unroll
    for (int p=0;p<16;p++){ uupk[p] = pkrtz(lrelu(uu[2*p]), lrelu(uu[2*p+1])); }

    if (occ){
        uint4* d = (uint4*)(uuo + ((size_t)li*8 + rk)*16);
        d[0] = make_uint4(uupk[0],uupk[1],uupk[2],uupk[3]);
        d[1] = make_uint4(uupk[4],uupk[5],uupk[6],uupk[7]);
        d[2] = make_uint4(uupk[8],uupk[9],uupk[10],uupk[11]);
        d[3] = make_uint4(uupk[12],uupk[13],uupk[14],uupk[15]);
    }

    // k row
    {
        float acc[32];
        #pragma unroll
        for (int h=0;h<32;h++) acc[h] = bk[h];
        #pragma unroll
        for (int p=0;p<16;p++){
            unsigned a = uupk[p];
            #pragma unroll
            for (int h=0;h<32;h++) acc[h] = fdot2(a, wk[p*32+h], acc[h]);
        }
        unsigned t[16];
        #pragma unroll
        for (int p=0;p<16;p++) t[p] = pkrtz(acc[2*p], acc[2*p+1]);
        uint4* d = (uint4*)(ku + ((size_t)j*cap + li)*16);
        d[0] = make_uint4(t[0],t[1],t[2],t[3]);
        d[1] = make_uint4(t[4],t[5],t[6],t[7]);
        d[2] = make_uint4(t[8],t[9],t[10],t[11]);
        d[3] = make_uint4(t[12],t[13],t[14],t[15]);
    }
    // v row
    {
        float acc[32];
        #pragma unroll
        for (int h=0;h<32;h++) acc[h] = bv[h];
        #pragma unroll
        for (int p=0;p<16;p++){
            unsigned a = uupk[p];
            #pragma unroll
            for (int h=0;h<32;h++) acc[h] = fdot2(a, wv[p*32+h], acc[h]);
        }
        unsigned t[16];
        #pragma unroll
        for (int p=0;p<16;p++) t[p] = pkrtz(acc[2*p], acc[2*p+1]);
        uint4* d = (uint4*)(vu + ((size_t)j*cap + li)*16);
        d[0] = make_uint4(t[0],t[1],t[2],t[3]);
        d[1] = make_uint4(t[4],t[5],t[6],t[7]);
        d[2] = make_uint4(t[8],t[9],t[10],t[11]);
        d[3] = make_uint4(t[12],t[13],t[14],t[15]);
    }
}

// ---------------- pass 2: one lane per (sample, query) -----------------------
__global__ __launch_bounds__(256,4)
void pass2_kernel(const unsigned* __restrict__ ku, const unsigned* __restrict__ vu,
                  const unsigned* __restrict__ uuo, const unsigned* __restrict__ upo,
                  const unsigned* __restrict__ ws32,
                  const float* __restrict__ bd1, const float* __restrict__ bd2,
                  const float* __restrict__ Ws, const float* __restrict__ bs,
                  float* __restrict__ out, int start, int n, long cap)
{
    int g = blockIdx.x*256 + threadIdx.x;
    if (g >= n*8) return;
    int sl = g >> 3, qi = g & 7;

    const unsigned* wq  = ws32 + OFF_WQ;
    const unsigned* wd1 = ws32 + OFF_WD1;
    const unsigned* wd2 = ws32 + OFF_WD2;
    const float*    bqs = (const float*)ws32 + OFF_BQS;

    // uu row (f16 pairs) -> q (scaled; scale folded into wq/bqs)
    unsigned uw[16];
    {
        const uint4* p4 = (const uint4*)(uuo + ((size_t)sl*8 + qi)*16);
        uint4 a = p4[0], b = p4[1], c = p4[2], d = p4[3];
        uw[0]=a.x; uw[1]=a.y; uw[2]=a.z; uw[3]=a.w;
        uw[4]=b.x; uw[5]=b.y; uw[6]=b.z; uw[7]=b.w;
        uw[8]=c.x; uw[9]=c.y; uw[10]=c.z; uw[11]=c.w;
        uw[12]=d.x; uw[13]=d.y; uw[14]=d.z; uw[15]=d.w;
    }
    float q[32];
    #pragma unroll
    for (int h=0;h<32;h++) q[h] = bqs[h];
    #pragma unroll
    for (int p=0;p<16;p++){
        unsigned a = uw[p];
        #pragma unroll
        for (int h=0;h<32;h++) q[h] = fdot2(a, wq[p*32+h], q[h]);
    }
    unsigned qpk[16];
    #pragma unroll
    for (int p=0;p<16;p++) qpk[p] = pkrtz(q[2*p], q[2*p+1]);

    // scores vs all 17 keys (lane-local row)
    float sc[JN];
    #pragma unroll
    for (int kj=0;kj<JN;kj++){
        const uint4* kp = (const uint4*)(ku + ((size_t)kj*cap + sl)*16);
        uint4 a = kp[0], b = kp[1], c = kp[2], d = kp[3];
        unsigned kw[16] = {a.x,a.y,a.z,a.w,b.x,b.y,b.z,b.w,c.x,c.y,c.z,c.w,d.x,d.y,d.z,d.w};
        float s0=0.f, s1=0.f;
        #pragma unroll
        for (int p=0;p<16;p+=2){
            s0 = fdot2(qpk[p],   kw[p],   s0);
            s1 = fdot2(qpk[p+1], kw[p+1], s1);
        }
        sc[kj] = s0 + s1;
    }
    float m = sc[0];
    #pragma unroll
    for (int kj=1;kj<JN;kj++) m = fmaxf(m, sc[kj]);
    float e[JN]; float sum = 0.f;
    #pragma unroll
    for (int kj=0;kj<JN;kj++){ e[kj] = __expf(sc[kj]-m); sum += e[kj]; }
    float ri = 1.0f/sum;

    // o = att @ v, accumulated as f16 pairs over h (feeds d1 dot2 directly)
    unsigned o[16];
    #pragma unroll
    for (int p=0;p<16;p++) o[p] = 0u;
    #pragma unroll
    for (int kj=0;kj<JN;kj++){
        float w = e[kj]*ri;
        unsigned w2 = pkrtz(w, w);
        const uint4* vp = (const uint4*)(vu + ((size_t)kj*cap + sl)*16);
        uint4 a = vp[0], b = vp[1], c = vp[2], d = vp[3];
        unsigned vw[16] = {a.x,a.y,a.z,a.w,b.x,b.y,b.z,b.w,c.x,c.y,c.z,c.w,d.x,d.y,d.z,d.w};
        #pragma unroll
        for (int p=0;p<16;p++) o[p] = pkfma(w2, vw[p], o[p]);
    }

    // d1 = leaky(o @ Wd1 + bd1)
    float t[32];
    #pragma unroll
    for (int h=0;h<32;h++) t[h] = bd1[h];
    #pragma unroll
    for (int p=0;p<16;p++){
        unsigned a = o[p];
        #pragma unroll
        for (int h=0;h<32;h++) t[h] = fdot2(a, wd1[p*32+h], t[h]);
    }
    unsigned tpk[16];
    #pragma unroll
    for (int p=0;p<16;p++) tpk[p] = pkrtz(lrelu(t[2*p]), lrelu(t[2*p+1]));

    // d2 + residual
    float z[32];
    {
        const uint4* p4 = (const uint4*)(upo + ((size_t)sl*8 + qi)*16);
        uint4 a = p4[0], b = p4[1], c = p4[2], d = p4[3];
        unsigned pw[16] = {a.x,a.y,a.z,a.w,b.x,b.y,b.z,b.w,c.x,c.y,c.z,c.w,d.x,d.y,d.z,d.w};
        #pragma unroll
        for (int p=0;p<16;p++){
            h2v r = u2h(pw[p]);
            z[2*p] = bd2[2*p] + (float)r.x; z[2*p+1] = bd2[2*p+1] + (float)r.y;
        }
    }
    #pragma unroll
    for (int p=0;p<16;p++){
        unsigned a = tpk[p];
        #pragma unroll
        for (int h=0;h<32;h++) z[h] = fdot2(a, wd2[p*32+h], z[h]);
    }

    // sigmoid(z @ Ws + bs)
    float y0=0.f, y1=0.f;
    #pragma unroll
    for (int h=0;h<32;h+=2){ y0 = fmaf(z[h], Ws[h], y0); y1 = fmaf(z[h+1], Ws[h+1], y1); }
    float y = y0 + y1 + bs[0];
    out[((size_t)(start + sl))*8 + qi] = 1.0f/(1.0f + __expf(-y));
}

extern "C" void kernel_launch(void* const* d_in, const int* in_sizes, int n_in,
                              void* d_out, int out_size, void* d_ws, size_t ws_size,
                              hipStream_t stream) {
    (void)n_in; (void)out_size;
    const float* x   = (const float*)d_in[0];
    const void*  m   = d_in[1];
    const float* pos = (const float*)d_in[2];
    const float* Wup = (const float*)d_in[3];  const float* bup = (const float*)d_in[4];
    const float* Wud = (const float*)d_in[5];  const float* bud = (const float*)d_in[6];
    const float* Wq  = (const float*)d_in[7];  const float* bq  = (const float*)d_in[8];
    const float* Wk  = (const float*)d_in[9];  const float* bk  = (const float*)d_in[10];
    const float* Wv  = (const float*)d_in[11]; const float* bv  = (const float*)d_in[12];
    const float* Wd1 = (const float*)d_in[13]; const float* bd1 = (const float*)d_in[14];
    const float* Wd2 = (const float*)d_in[15]; const float* bd2 = (const float*)d_in[16];
    const float* Ws  = (const float*)d_in[17]; const float* bs  = (const float*)d_in[18];
    float* out = (float*)d_out;
    int B = in_sizes[0] / (JN*2);

    unsigned char* wsb = (unsigned char*)d_ws;
    unsigned* ws32  = (unsigned*)wsb;                           // 64 KB header
    unsigned* bmask = (unsigned*)(wsb + HDR_BYTES);             // B u32
    size_t data_off = (HDR_BYTES + (size_t)B*4 + 255) & ~(size_t)255;
    // per-sample ws: k (17*16) + v (17*16) + uuo 128 + upo 128 = 800 u32 = 3200 B
    long cap = 0;
    if (ws_size > data_off) cap = (long)((ws_size - data_off) / 3200);
    cap = (cap/64)*64;
    if (cap <= 0) return;
    if (cap > B) cap = (long)B;
    unsigned* ku  = (unsigned*)(wsb + data_off);
    unsigned* vu  = ku  + (size_t)cap*272;
    unsigned* uuo = ku  + (size_t)cap*544;
    unsigned* upo = ku  + (size_t)cap*672;

    prep_kernel<<<(B+255)/256, 256, 0, stream>>>(m, pos, Wup, Wud, bud, Wq, bq,
                                                 Wk, Wv, Wd1, Wd2, ws32, bmask, B);
    for (long start = 0; start < B; start += cap){
        int n = (int)((B - start < cap) ? (B - start) : cap);
        dim3 g1((n+255)/256, JN);
        pass1_kernel<<<g1, 256, 0, stream>>>(x, bmask, ws32, bup, bk, bv,
                                             ku, vu, uuo, upo, (int)start, n, cap);
        pass2_kernel<<<(n*8+255)/256, 256, 0, stream>>>(ku, vu, uuo, upo, ws32,
                                                        bd1, bd2, Ws, bs,
                                                        out, (int)start, n, cap);
    }
}